// Round 6
// baseline (123.165 us; speedup 1.0000x reference)
//
#include <hip/hip_runtime.h>
#include <hip/hip_bf16.h>

// Problem constants (B, NBC, H, W, HID, OUT = 4, 128, 64, 64, 64, 1)
// ALL tensors are float32 (reference uses jnp.float32 throughout).
#define BB   4
#define NBC  128
#define NINT 4096
#define HID  64

using short8  = __attribute__((ext_vector_type(8)))  short;  // 8 bf16 (4 VGPRs)
using float16 = __attribute__((ext_vector_type(16))) float;  // MFMA 32x32 acc

static __device__ __forceinline__ short f2bf(float f) {  // RNE, used for weights
    __hip_bfloat16 h = __float2bfloat16(f);
    return __builtin_bit_cast(short, h);
}
static __device__ __forceinline__ unsigned fbits(float f) {
    return __builtin_bit_cast(unsigned, f);
}
// pack trunc-bf16(lo), trunc-bf16(hi) into one dword: D = [hi31:16 | lo31:16]
static __device__ __forceinline__ unsigned pack_bf_trunc(float lo, float hi) {
    return __builtin_amdgcn_perm(fbits(hi), fbits(lo), 0x07060302u);
}

// ---------------------------------------------------------------------------
// Kernel 1: boundary encoder + a' = relu(relu(x@W0+b0)@W1+b1) @ G0w[:64] + G0b
// 128 blocks x 256 threads; wave w computes row blockIdx*4+w. (unchanged, fast)
// ---------------------------------------------------------------------------
__global__ void __launch_bounds__(256) bge_prep(
    const float* __restrict__ binfo,  // (4,128,3)
    const float* __restrict__ W0,     // (3,64)
    const float* __restrict__ b0,     // (64)
    const float* __restrict__ W1,     // (64,64)
    const float* __restrict__ b1,     // (64)
    const float* __restrict__ G0w,    // (66,64)
    const float* __restrict__ G0b,    // (64)
    float* __restrict__ aprime)       // (4,128,64)
{
    __shared__ float sW1[HID * HID];   // 16 KB
    __shared__ float sG0[HID * HID];   // 16 KB
    __shared__ float shv [4][HID];
    __shared__ float shv2[4][HID];

    const int tid = threadIdx.x;
    const int wv  = tid >> 6;
    const int t   = tid & 63;
    const int row = blockIdx.x * 4 + wv;

    for (int idx = tid; idx < HID * HID / 4; idx += 256) {
        ((float4*)sW1)[idx] = ((const float4*)W1)[idx];
        ((float4*)sG0)[idx] = ((const float4*)G0w)[idx];
    }

    const float x0 = binfo[row*3+0];
    const float x1 = binfo[row*3+1];
    const float x2 = binfo[row*3+2];
    float h = fmaxf(x0*W0[t] + x1*W0[64+t] + x2*W0[128+t] + b0[t], 0.0f);
    shv[wv][t] = h;
    __syncthreads();                       // covers sW1/sG0 staging + shv

    float acc = b1[t];
    #pragma unroll 8
    for (int k = 0; k < HID; ++k) acc += shv[wv][k] * sW1[k*64 + t];
    shv2[wv][t] = fmaxf(acc, 0.0f);
    __syncthreads();

    float a = G0b[t];
    #pragma unroll 8
    for (int k = 0; k < HID; ++k) a += shv2[wv][k] * sG0[k*64 + t];
    aprime[row*HID + t] = a;
}

// ---------------------------------------------------------------------------
// Kernel 2 (RESTRUCTURED, round 6): transposed MFMA roles.
//   A-operand = G1w^T (weights, loaded once/wave), B-operand = h1^T per bc.
//   D[m=n][col=i]: col=lane&31 = interior point, rows = hidden n in regs.
//   Bias b1 folded via precomputed bias MFMA tiles used as the C-operand of
//   each bc chain's first MFMA. No LDS in the main loop; a' rows read as
//   per-lane float4 global loads (L2-broadcast). Epilogue: relu + fma with
//   per-reg g2 constants, 4 rotating accumulators.
// grid (128, 4); 256 threads = 4 waves; wave wv handles bc [32wv, 32wv+32).
// NOTE: no second __launch_bounds__ arg — R4 showed it forces spills.
// MFMA 32x32x16 bf16 mappings [verified R2-R5]:
//   A[m=lane&31][k=hf*8+jj(+16st)], B[k=hf*8+jj(+16st)][n=lane&31],
//   C/D: col=lane&31, row=(reg&3)+8*(reg>>2)+4*hf.
// ---------------------------------------------------------------------------
__global__ void __launch_bounds__(256) bge_main(
    const float* __restrict__ icoord, // (4,4096,2)
    const float* __restrict__ G0w,    // (66,64)  rows 64,65 used here
    const float* __restrict__ G1w,    // (64,64)
    const float* __restrict__ G1b,    // (64)
    const float* __restrict__ G2w,    // (64,1)
    const float* __restrict__ G2b,    // (1)
    const float* __restrict__ aprime, // (4,128,64) fp32
    float* __restrict__ out)          // (4,4096)
{
    __shared__ float sred[4][64];

    const int b    = blockIdx.y;
    const int i0   = blockIdx.x * 32;
    const int tid  = threadIdx.x;
    const int wv   = tid >> 6;       // 0..3
    const int lane = tid & 63;
    const int hf   = lane >> 5;
    const int ln   = lane & 31;

    // per-lane c contribution: cre[st][jj] for k = st*16 + hf*8 + jj, i = i0+ln
    const float2 cc = ((const float2*)icoord)[(size_t)b*NINT + i0 + ln];
    float cre[4][8];
    #pragma unroll
    for (int st = 0; st < 4; ++st)
        #pragma unroll
        for (int jj = 0; jj < 8; ++jj) {
            const int k = st*16 + hf*8 + jj;
            cre[st][jj] = cc.x*G0w[64*64 + k] + cc.y*G0w[65*64 + k];
        }

    // A-operand fragments of G1w^T (tile t covers n in [32t,32t+32)):
    // A[m=ln][k] = G1w[k*64 + 32t + ln]  (same load pattern as verified bfrag)
    short8 afr[2][4];
    #pragma unroll
    for (int t = 0; t < 2; ++t)
        #pragma unroll
        for (int st = 0; st < 4; ++st)
            #pragma unroll
            for (int jj = 0; jj < 8; ++jj) {
                const int k = st*16 + hf*8 + jj;
                afr[t][st][jj] = f2bf(G1w[k*64 + t*32 + ln]);
            }

    // per-(tile,reg) g2 constants: row(r) = (r&3)+8*(r>>2)+4*hf
    float g2c[2][16];
    #pragma unroll
    for (int t = 0; t < 2; ++t)
        #pragma unroll
        for (int r = 0; r < 16; ++r)
            g2c[t][r] = G2w[(r&3) + 8*(r>>2) + 4*hf + 32*t];

    // bias tiles via one-time MFMA: D[m][*] = b1[32t+m]
    float16 accb0, accb1;
    {
        short8 afb0 = (short8)0, afb1 = (short8)0, bone = (short8)0;
        if (hf == 0) {
            afb0[0] = f2bf(G1b[ln]);
            afb1[0] = f2bf(G1b[32 + ln]);
            bone[0] = (short)0x3F80;   // bf16 1.0
        }
        const float16 zc = (float16)0.0f;
        accb0 = __builtin_amdgcn_mfma_f32_32x32x16_bf16(afb0, bone, zc, 0, 0, 0);
        accb1 = __builtin_amdgcn_mfma_f32_32x32x16_bf16(afb1, bone, zc, 0, 0, 0);
    }

    float s0 = 0.0f, s1 = 0.0f, s2 = 0.0f, s3 = 0.0f;

    const float* arow = aprime + ((size_t)b*NBC + wv*32)*HID;
    #pragma unroll 2
    for (int it = 0; it < 32; ++it, arow += HID) {
        // build B-fragments (h1^T): B[k][i=ln] = relu(a'[bc][k] + c[i][k])
        short8 bf[4];
        #pragma unroll
        for (int st = 0; st < 4; ++st) {
            const float4 v0 = *(const float4*)(arow + st*16 + hf*8);
            const float4 v1 = *(const float4*)(arow + st*16 + hf*8 + 4);
            const float e0 = fmaxf(v0.x + cre[st][0], 0.0f);
            const float e1 = fmaxf(v0.y + cre[st][1], 0.0f);
            const float e2 = fmaxf(v0.z + cre[st][2], 0.0f);
            const float e3 = fmaxf(v0.w + cre[st][3], 0.0f);
            const float e4 = fmaxf(v1.x + cre[st][4], 0.0f);
            const float e5 = fmaxf(v1.y + cre[st][5], 0.0f);
            const float e6 = fmaxf(v1.z + cre[st][6], 0.0f);
            const float e7 = fmaxf(v1.w + cre[st][7], 0.0f);
            int di0 = (int)pack_bf_trunc(e0, e1);
            int di1 = (int)pack_bf_trunc(e2, e3);
            int di2 = (int)pack_bf_trunc(e4, e5);
            int di3 = (int)pack_bf_trunc(e6, e7);
            bf[st][0] = (short)(di0 & 0xFFFF); bf[st][1] = (short)(((unsigned)di0) >> 16);
            bf[st][2] = (short)(di1 & 0xFFFF); bf[st][3] = (short)(((unsigned)di1) >> 16);
            bf[st][4] = (short)(di2 & 0xFFFF); bf[st][5] = (short)(((unsigned)di2) >> 16);
            bf[st][6] = (short)(di3 & 0xFFFF); bf[st][7] = (short)(((unsigned)di3) >> 16);
        }
        // MFMA chains, C-init = bias tiles (b1 pre-added before relu)
        float16 acc0 = __builtin_amdgcn_mfma_f32_32x32x16_bf16(afr[0][0], bf[0], accb0, 0, 0, 0);
        float16 acc1 = __builtin_amdgcn_mfma_f32_32x32x16_bf16(afr[1][0], bf[0], accb1, 0, 0, 0);
        #pragma unroll
        for (int st = 1; st < 4; ++st) {
            acc0 = __builtin_amdgcn_mfma_f32_32x32x16_bf16(afr[0][st], bf[st], acc0, 0, 0, 0);
            acc1 = __builtin_amdgcn_mfma_f32_32x32x16_bf16(afr[1][st], bf[st], acc1, 0, 0, 0);
        }
        // epilogue: s += relu(h2+b1) * g2, rotating accumulators
        #pragma unroll
        for (int r = 0; r < 16; r += 4) {
            s0 += fmaxf(acc0[r+0], 0.0f)*g2c[0][r+0] + fmaxf(acc1[r+0], 0.0f)*g2c[1][r+0];
            s1 += fmaxf(acc0[r+1], 0.0f)*g2c[0][r+1] + fmaxf(acc1[r+1], 0.0f)*g2c[1][r+1];
            s2 += fmaxf(acc0[r+2], 0.0f)*g2c[0][r+2] + fmaxf(acc1[r+2], 0.0f)*g2c[1][r+2];
            s3 += fmaxf(acc0[r+3], 0.0f)*g2c[0][r+3] + fmaxf(acc1[r+3], 0.0f)*g2c[1][r+3];
        }
    }

    sred[wv][lane] = (s0 + s1) + (s2 + s3);
    __syncthreads();

    if (tid < 32) {   // combine 4 waves x 2 half-wave partials per i
        float tot = 0.0f;
        #pragma unroll
        for (int w = 0; w < 4; ++w) tot += sred[w][tid] + sred[w][tid + 32];
        out[(size_t)b*NINT + i0 + tid] = tot * (1.0f/128.0f) + G2b[0];
    }
}

// ---------------------------------------------------------------------------
extern "C" void kernel_launch(void* const* d_in, const int* in_sizes, int n_in,
                              void* d_out, int out_size, void* d_ws, size_t ws_size,
                              hipStream_t stream) {
    const float* binfo  = (const float*)d_in[0];
    const float* icoord = (const float*)d_in[1];
    const float* W0     = (const float*)d_in[2];
    const float* b0     = (const float*)d_in[3];
    const float* W1     = (const float*)d_in[4];
    const float* b1     = (const float*)d_in[5];
    const float* G0w    = (const float*)d_in[6];
    const float* G0b    = (const float*)d_in[7];
    const float* G1w    = (const float*)d_in[8];
    const float* G1b    = (const float*)d_in[9];
    const float* G2w    = (const float*)d_in[10];
    const float* G2b    = (const float*)d_in[11];

    float* aprime = (float*)d_ws;   // 4*128*64 fp32 = 128 KB scratch

    hipLaunchKernelGGL(bge_prep, dim3(BB*NBC/4), dim3(256), 0, stream,
                       binfo, W0, b0, W1, b1, G0w, G0b, aprime);
    hipLaunchKernelGGL(bge_main, dim3(NINT/32, BB), dim3(256), 0, stream,
                       icoord, G0w, G1w, G1b, G2w, G2b, aprime,
                       (float*)d_out);
}

// Round 7
// 120.951 us; speedup vs baseline: 1.0183x; 1.0183x over previous
//
#include <hip/hip_runtime.h>
#include <hip/hip_bf16.h>

// Problem constants (B, NBC, H, W, HID, OUT = 4, 128, 64, 64, 64, 1)
// ALL tensors are float32 (reference uses jnp.float32 throughout).
#define BB   4
#define NBC  128
#define NINT 4096
#define HID  64

using short8  = __attribute__((ext_vector_type(8)))  short;  // 8 bf16 (4 VGPRs)
using float4v = __attribute__((ext_vector_type(4)))  float;  // 16x16 MFMA acc
using f2      = __attribute__((ext_vector_type(2)))  float;
using int4v   = __attribute__((ext_vector_type(4)))  int;

static __device__ __forceinline__ short f2bf(float f) {  // RNE, weights only
    __hip_bfloat16 h = __float2bfloat16(f);
    return __builtin_bit_cast(short, h);
}
static __device__ __forceinline__ unsigned fbits(float f) {
    return __builtin_bit_cast(unsigned, f);
}
// pack trunc-bf16(lo), trunc-bf16(hi) into one dword (verified R2-R6)
static __device__ __forceinline__ unsigned pack_bf_trunc(float lo, float hi) {
    return __builtin_amdgcn_perm(fbits(hi), fbits(lo), 0x07060302u);
}

// ---------------------------------------------------------------------------
// Kernel 1: boundary encoder + a' -> ws; ALSO zero-inits out (for atomics).
// 128 blocks x 256 threads; wave w computes row blockIdx*4+w.
// ---------------------------------------------------------------------------
__global__ void __launch_bounds__(256) bge_prep(
    const float* __restrict__ binfo,  // (4,128,3)
    const float* __restrict__ W0,     // (3,64)
    const float* __restrict__ b0,     // (64)
    const float* __restrict__ W1,     // (64,64)
    const float* __restrict__ b1,     // (64)
    const float* __restrict__ G0w,    // (66,64)
    const float* __restrict__ G0b,    // (64)
    float* __restrict__ aprime,       // (4,128,64)
    float* __restrict__ out)          // (4,4096) -> zeroed here
{
    __shared__ float sW1[HID * HID];
    __shared__ float sG0[HID * HID];
    __shared__ float shv [4][HID];
    __shared__ float shv2[4][HID];

    const int tid = threadIdx.x;
    const int wv  = tid >> 6;
    const int t   = tid & 63;
    const int row = blockIdx.x * 4 + wv;

    // zero the output (harness poisons it 0xAA before every launch)
    const int g = blockIdx.x * 256 + tid;
    if (g < BB * NINT) out[g] = 0.0f;

    for (int idx = tid; idx < HID * HID / 4; idx += 256) {
        ((float4*)sW1)[idx] = ((const float4*)W1)[idx];
        ((float4*)sG0)[idx] = ((const float4*)G0w)[idx];
    }

    const float x0 = binfo[row*3+0];
    const float x1 = binfo[row*3+1];
    const float x2 = binfo[row*3+2];
    float h = fmaxf(x0*W0[t] + x1*W0[64+t] + x2*W0[128+t] + b0[t], 0.0f);
    shv[wv][t] = h;
    __syncthreads();

    float acc = b1[t];
    #pragma unroll 8
    for (int k = 0; k < HID; ++k) acc += shv[wv][k] * sW1[k*64 + t];
    shv2[wv][t] = fmaxf(acc, 0.0f);
    __syncthreads();

    float a = G0b[t];
    #pragma unroll 8
    for (int k = 0; k < HID; ++k) a += shv2[wv][k] * sG0[k*64 + t];
    aprime[row*HID + t] = a;
}

// ---------------------------------------------------------------------------
// Kernel 2 (R7): 16x16x32 MFMA, sequential chains, lean registers.
//   grid (128, 4, 2): i-tile of 32, batch, bc-half. 256 thr = 4 waves;
//   wave wv handles bc [zh*64 + wv*16, +16).
//   Lane: ln = lane&15 (n / i col), q = lane>>4 (quad).
//   A-frag (h1): A[m=ln][k=q*8+jj] for i-half ih, k-half kh.
//   B-frag (G1w): B[k=q*8+jj][n=ln] per (kh, n-tile nt).
//   C/D: col(n)=ln, row(i)=q*4+reg  [guide m89].
//   Bias: relu(x+b) = max(x,-b)+b -> epilogue max vs -b1, exact corr added once.
//   Out combined across the 2 bc-halves via atomicAdd (out zeroed in prep).
// ---------------------------------------------------------------------------
__global__ void __launch_bounds__(256) bge_main(
    const float* __restrict__ icoord, // (4,4096,2)
    const float* __restrict__ G0w,    // (66,64)  rows 64,65 used here
    const float* __restrict__ G1w,    // (64,64)
    const float* __restrict__ G1b,    // (64)
    const float* __restrict__ G2w,    // (64,1)
    const float* __restrict__ G2b,    // (1)
    const float* __restrict__ aprime, // (4,128,64) fp32
    float* __restrict__ out)          // (4,4096), pre-zeroed
{
    __shared__ float sred[4][32];

    const int b    = blockIdx.y;
    const int i0   = blockIdx.x * 32;
    const int zh   = blockIdx.z;     // bc half (0/1)
    const int tid  = threadIdx.x;
    const int wv   = tid >> 6;       // 0..3
    const int lane = tid & 63;
    const int ln   = lane & 15;
    const int q    = lane >> 4;      // 0..3

    // coords for this lane's two i values (i-halves)
    const float2 cc0 = ((const float2*)icoord)[(size_t)b*NINT + i0 + ln];
    const float2 cc1 = ((const float2*)icoord)[(size_t)b*NINT + i0 + 16 + ln];

    // cre[ih][kh][pair]: c-contribution for k = kh*32 + q*8 + jj
    f2 cre[2][2][4];
    #pragma unroll
    for (int kh = 0; kh < 2; ++kh)
        #pragma unroll
        for (int jj = 0; jj < 8; ++jj) {
            const int k = kh*32 + q*8 + jj;
            const float gx = G0w[64*64 + k], gy = G0w[65*64 + k];
            cre[0][kh][jj>>1][jj&1] = cc0.x*gx + cc0.y*gy;
            cre[1][kh][jj>>1][jj&1] = cc1.x*gx + cc1.y*gy;
        }

    // B fragments of G1w: bfrag[kh][nt]
    short8 bfrag[2][4];
    #pragma unroll
    for (int kh = 0; kh < 2; ++kh)
        #pragma unroll
        for (int nt = 0; nt < 4; ++nt)
            #pragma unroll
            for (int jj = 0; jj < 8; ++jj)
                bfrag[kh][nt][jj] = f2bf(G1w[(kh*32 + q*8 + jj)*64 + nt*16 + ln]);

    // per-lane n-constants and exact bias correction
    float nb1[4], g2v[4];
    float corr = 0.0f;
    #pragma unroll
    for (int nt = 0; nt < 4; ++nt) {
        const float bv = G1b[nt*16 + ln];
        const float gv = G2w[nt*16 + ln];
        nb1[nt] = -bv;  g2v[nt] = gv;  corr += bv * gv;
    }

    f2 s[2][2];
    s[0][0] = (f2)0.0f; s[0][1] = (f2)0.0f; s[1][0] = (f2)0.0f; s[1][1] = (f2)0.0f;
    const float4v zc4 = (float4v)0.0f;

    const float* arow = aprime + ((size_t)b*NBC + zh*64 + wv*16)*HID;
    #pragma unroll 1
    for (int it = 0; it < 16; ++it, arow += HID) {
        // build A fragments (h1) for both i-halves and k-halves
        short8 af[2][2];
        #pragma unroll
        for (int kh = 0; kh < 2; ++kh) {
            const float4 v0 = *(const float4*)(arow + kh*32 + q*8);
            const float4 v1 = *(const float4*)(arow + kh*32 + q*8 + 4);
            f2 w[4];
            w[0][0]=v0.x; w[0][1]=v0.y; w[1][0]=v0.z; w[1][1]=v0.w;
            w[2][0]=v1.x; w[2][1]=v1.y; w[3][0]=v1.z; w[3][1]=v1.w;
            #pragma unroll
            for (int ih = 0; ih < 2; ++ih) {
                const f2 e0 = w[0] + cre[ih][kh][0];
                const f2 e1 = w[1] + cre[ih][kh][1];
                const f2 e2 = w[2] + cre[ih][kh][2];
                const f2 e3 = w[3] + cre[ih][kh][3];
                int4v di;
                di[0] = (int)pack_bf_trunc(fmaxf(e0[0],0.f), fmaxf(e0[1],0.f));
                di[1] = (int)pack_bf_trunc(fmaxf(e1[0],0.f), fmaxf(e1[1],0.f));
                di[2] = (int)pack_bf_trunc(fmaxf(e2[0],0.f), fmaxf(e2[1],0.f));
                di[3] = (int)pack_bf_trunc(fmaxf(e3[0],0.f), fmaxf(e3[1],0.f));
                af[ih][kh] = __builtin_bit_cast(short8, di);
            }
        }
        // 8 short chains: (i-half, n-tile), one 4-reg acc at a time
        #pragma unroll
        for (int ih = 0; ih < 2; ++ih)
            #pragma unroll
            for (int nt = 0; nt < 4; ++nt) {
                float4v acc = __builtin_amdgcn_mfma_f32_16x16x32_bf16(
                                  af[ih][0], bfrag[0][nt], zc4, 0, 0, 0);
                acc = __builtin_amdgcn_mfma_f32_16x16x32_bf16(
                                  af[ih][1], bfrag[1][nt], acc, 0, 0, 0);
                f2 m0, m1;
                m0[0] = fmaxf(acc[0], nb1[nt]); m0[1] = fmaxf(acc[1], nb1[nt]);
                m1[0] = fmaxf(acc[2], nb1[nt]); m1[1] = fmaxf(acc[3], nb1[nt]);
                s[ih][0] += m0 * g2v[nt];
                s[ih][1] += m1 * g2v[nt];
            }
    }

    // exact bias correction: each s element covered 16 bc x 4 n-tiles
    const f2 cadd = (f2)(16.0f * corr);
    s[0][0] += cadd; s[0][1] += cadd; s[1][0] += cadd; s[1][1] += cadd;

    // reduce over n within each 16-lane group (butterfly), then LDS + atomic
    float v8[8] = { s[0][0][0], s[0][0][1], s[0][1][0], s[0][1][1],
                    s[1][0][0], s[1][0][1], s[1][1][0], s[1][1][1] };
    #pragma unroll
    for (int t = 0; t < 8; ++t) {
        float v = v8[t];
        v += __shfl_xor(v, 1);
        v += __shfl_xor(v, 2);
        v += __shfl_xor(v, 4);
        v += __shfl_xor(v, 8);
        v8[t] = v;
    }
    if (ln == 0) {
        #pragma unroll
        for (int ih = 0; ih < 2; ++ih)
            #pragma unroll
            for (int r = 0; r < 4; ++r)
                sred[wv][ih*16 + q*4 + r] = v8[ih*4 + r];
    }
    __syncthreads();

    if (tid < 32) {
        const float tot = sred[0][tid] + sred[1][tid] + sred[2][tid] + sred[3][tid];
        atomicAdd(out + (size_t)b*NINT + i0 + tid,
                  tot * (1.0f/128.0f) + 0.5f * G2b[0]);
    }
}

// ---------------------------------------------------------------------------
extern "C" void kernel_launch(void* const* d_in, const int* in_sizes, int n_in,
                              void* d_out, int out_size, void* d_ws, size_t ws_size,
                              hipStream_t stream) {
    const float* binfo  = (const float*)d_in[0];
    const float* icoord = (const float*)d_in[1];
    const float* W0     = (const float*)d_in[2];
    const float* b0     = (const float*)d_in[3];
    const float* W1     = (const float*)d_in[4];
    const float* b1     = (const float*)d_in[5];
    const float* G0w    = (const float*)d_in[6];
    const float* G0b    = (const float*)d_in[7];
    const float* G1w    = (const float*)d_in[8];
    const float* G1b    = (const float*)d_in[9];
    const float* G2w    = (const float*)d_in[10];
    const float* G2b    = (const float*)d_in[11];

    float* aprime = (float*)d_ws;   // 4*128*64 fp32 = 128 KB scratch

    hipLaunchKernelGGL(bge_prep, dim3(BB*NBC/4), dim3(256), 0, stream,
                       binfo, W0, b0, W1, b1, G0w, G0b, aprime, (float*)d_out);
    hipLaunchKernelGGL(bge_main, dim3(NINT/32, BB, 2), dim3(256), 0, stream,
                       icoord, G0w, G1w, G1b, G2w, G2b, aprime,
                       (float*)d_out);
}